// Round 11
// baseline (32.326 us; speedup 1.0000x reference)
//
#include <hip/hip_runtime.h>

// ParticleI2cCell: pairwise Gaussian loglik (P x P, D=4) + two row-LSEs.
// smoothed[i] = log(sum_j e_ij*exp(w_j)) - log(sum_j e_ij*exp(lw_j))
// e_ij = exp(m_i . s_j - ||s_j||^2/2)   [exp(-||m_i||^2/2) cancels in the
// log-ratio and is dropped].
//
// R10 lesson: four different structures (LDS-feed / VMEM-feed / 2x occupancy
// / half traffic) all land at ~25us pair time with VALUBusy ~25%. The
// invariant is the 1.05M wave-level v_exp_f32 ops: implied effective
// throughput ~1.4 lanes/cyc/SIMD — the trans pipe is the floor.
// R11: replace v_exp_f32 with a full-rate VALU polynomial exp2
// (rndne + sub + 4 FMA + cvt_i32 + ldexp = 8 VALU ops, rel err ~5e-5).
// Per pair: 14 VALU, 0 trans -> issue floor ~12us regardless of whether the
// trans pipe blocks issue or not.

constexpr float LOG2E = 1.4426950408889634f;
constexpr float LN2   = 0.6931471805599453f;

// 2^f Taylor-4 coefficients c_k = (ln2)^k / k!
constexpr float EC1 = 0.6931471805599453f;
constexpr float EC2 = 0.2402265069591007f;
constexpr float EC3 = 0.0555041086648216f;
constexpr float EC4 = 0.0096181291076285f;

// full-rate VALU exp2: no transcendental instructions
__device__ __forceinline__ float exp2_poly(float t) {
    float n = __builtin_rintf(t);          // v_rndne_f32
    float f = t - n;                       // v_sub_f32, f in [-0.5, 0.5]
    float p = __builtin_fmaf(f, EC4, EC3); // 4x v_fma_f32
    p = __builtin_fmaf(f, p, EC2);
    p = __builtin_fmaf(f, p, EC1);
    p = __builtin_fmaf(f, p, 1.0f);
    int ni = (int)n;                       // v_cvt_i32_f32 (n integral: exact)
    return __builtin_amdgcn_ldexpf(p, ni); // v_ldexp_f32
}

// ---------------- precompute: j-table [P][8] AoS + means SoA [4][P] --------
__global__ __launch_bounds__(256) void precompute_k(
    const float* __restrict__ particles,
    const float* __restrict__ samples,
    const float* __restrict__ weights,
    const float* __restrict__ log_weights,
    const float* __restrict__ A,
    const float* __restrict__ B,
    const float* __restrict__ log_sigma,
    float* __restrict__ jdata,   // [P][8]: {LOG2E*s0..s3, K*||s||^2, e^lw, e^w, 0}
    float* __restrict__ msoa,    // [4][P] scaled means
    int P)
{
    int i = blockIdx.x * blockDim.x + threadIdx.x;
    if (i >= P) return;

    const float K = -0.5f * LOG2E;

    float inv_s[4];
#pragma unroll
    for (int k = 0; k < 4; ++k)
        inv_s[k] = __builtin_amdgcn_exp2f(-log_sigma[k] * LOG2E);

    float4 sv = reinterpret_cast<const float4*>(samples)[i];
    float s0 = sv.x * inv_s[0], s1 = sv.y * inv_s[1];
    float s2 = sv.z * inv_s[2], s3 = sv.w * inv_s[3];
    float sn = s0*s0 + s1*s1 + s2*s2 + s3*s3;

    float4* jd = reinterpret_cast<float4*>(jdata + (size_t)i * 8);
    jd[0] = make_float4(LOG2E*s0, LOG2E*s1, LOG2E*s2, LOG2E*s3);
    jd[1] = make_float4(K * sn,
                        __builtin_amdgcn_exp2f(log_weights[i] * LOG2E),
                        __builtin_amdgcn_exp2f(weights[i] * LOG2E),
                        0.f);

    const float2* p2 = reinterpret_cast<const float2*>(particles) + (size_t)i * 3;
    float2 x01 = p2[0], x23 = p2[1], u01 = p2[2];
    float x[4] = {x01.x, x01.y, x23.x, x23.y};
    float u[2] = {u01.x, u01.y};
#pragma unroll
    for (int k = 0; k < 4; ++k) {
        float mean =       A[k*4+0] * x[0];
        mean = fmaf(A[k*4+1], x[1], mean);
        mean = fmaf(A[k*4+2], x[2], mean);
        mean = fmaf(A[k*4+3], x[3], mean);
        mean = fmaf(B[k*2+0], u[0], mean);
        mean = fmaf(B[k*2+1], u[1], mean);
        msoa[(size_t)k * P + i] = mean * inv_s[k];
    }
}

// ---------------- fused pair + in-block reduce -----------------------------
// grid = P/TR = 1024 blocks of 256 -> 4 blocks/CU, 16 waves/CU.
// Thread t sweeps j = t + BLOCK*it; TR=8 block-uniform row means.
template <int TR, int BLOCK>
__global__ __launch_bounds__(BLOCK, 4) void pair_fused(
    const float* __restrict__ jdata,   // [P][8]
    const float* __restrict__ msoa,    // [4][P]
    float* __restrict__ out, int P)
{
    constexpr int NW = BLOCK / 64;

    const int tid  = threadIdx.x;
    const int lane = tid & 63;
    const int wv   = tid >> 6;
    const int rowBase = blockIdx.x * TR;

    // block-uniform row means -> scalar loads / SGPRs
    float m0[TR], m1[TR], m2[TR], m3[TR], a1[TR], a2[TR];
#pragma unroll
    for (int r = 0; r < TR; ++r) {
        m0[r] = msoa[0 * (size_t)P + rowBase + r];
        m1[r] = msoa[1 * (size_t)P + rowBase + r];
        m2[r] = msoa[2 * (size_t)P + rowBase + r];
        m3[r] = msoa[3 * (size_t)P + rowBase + r];
        a1[r] = 0.f;
        a2[r] = 0.f;
    }

    // per-lane coalesced j-walk: 2 x dwordx4 per j from L1/L2
    const float4* jf = reinterpret_cast<const float4*>(jdata);
    const int iters = P / BLOCK;     // 32 at P=8192
#pragma unroll 4
    for (int it = 0; it < iters; ++it) {
        const int j = it * BLOCK + tid;
        float4 av = jf[2 * j];
        float4 bv = jf[2 * j + 1];
#pragma unroll
        for (int r = 0; r < TR; ++r) {
            float t = fmaf(m0[r], av.x, bv.x);
            t = fmaf(m1[r], av.y, t);
            t = fmaf(m2[r], av.z, t);
            t = fmaf(m3[r], av.w, t);
            float e = exp2_poly(t);
            a1[r] = fmaf(e, bv.y, a1[r]);
            a2[r] = fmaf(e, bv.z, a2[r]);
        }
    }

    // ---- 64-lane butterfly per row (fixed order -> deterministic) ----
#pragma unroll
    for (int r = 0; r < TR; ++r) {
#pragma unroll
        for (int mask = 32; mask >= 1; mask >>= 1) {
            a1[r] += __shfl_xor(a1[r], mask, 64);
            a2[r] += __shfl_xor(a2[r], mask, 64);
        }
    }

    // ---- cross-wave combine via small LDS, fixed order ----
    __shared__ float red[NW][2 * TR];
    if (lane == 0) {
#pragma unroll
        for (int r = 0; r < TR; ++r) {
            red[wv][r]      = a1[r];
            red[wv][TR + r] = a2[r];
        }
    }
    __syncthreads();
    if (tid < TR) {
        float s1 = 0.f, s2 = 0.f;
#pragma unroll
        for (int w = 0; w < NW; ++w) {
            s1 += red[w][tid];
            s2 += red[w][TR + tid];
        }
        out[rowBase + tid] =
            (__builtin_amdgcn_logf(s2) - __builtin_amdgcn_logf(s1)) * LN2;
    }
}

extern "C" void kernel_launch(void* const* d_in, const int* in_sizes, int n_in,
                              void* d_out, int out_size, void* d_ws, size_t ws_size,
                              hipStream_t stream)
{
    const float* particles   = (const float*)d_in[0];
    const float* samples     = (const float*)d_in[1];
    const float* weights     = (const float*)d_in[2];
    const float* log_weights = (const float*)d_in[3];
    const float* A           = (const float*)d_in[4];
    const float* B           = (const float*)d_in[5];
    const float* log_sigma   = (const float*)d_in[6];

    const int P = in_sizes[2];  // weights is (P,)

    // ws layout: jdata P*8 | msoa 4*P   (393 KB at P=8192)
    float* jdata = (float*)d_ws;
    float* msoa  = jdata + (size_t)P * 8;

    constexpr int BLOCK = 256, TR = 8;

    precompute_k<<<(P + 255) / 256, 256, 0, stream>>>(
        particles, samples, weights, log_weights, A, B, log_sigma,
        jdata, msoa, P);

    pair_fused<TR, BLOCK><<<P / TR, BLOCK, 0, stream>>>(
        jdata, msoa, (float*)d_out, P);
}

// Round 12
// 32.146 us; speedup vs baseline: 1.0056x; 1.0056x over previous
//
#include <hip/hip_runtime.h>

// ParticleI2cCell: pairwise Gaussian loglik (P x P, D=4) + two row-LSEs.
// smoothed[i] = log(sum_j e_ij*exp(w_j)) - log(sum_j e_ij*exp(lw_j))
// e_ij = exp(m_i . s_j - ||s_j||^2/2)   [exp(-||m_i||^2/2) cancels in the
// log-ratio and is dropped].
//
// R11 lessons: trans pipe NOT the floor (poly-exp was slower); VALU issue
// NOT the floor (2x ops -> only +5us). Clean data: R5 (2 waves/SIMD, 52us)
// -> R8 (4 waves/SIMD, ~24us pair) scales 2x with occupancy; R9's "8 waves"
// test was invalid (launch_bounds(512,8) = 64-VGPR cap -> spill). R12 runs
// the 8-waves/SIMD experiment properly: TR=8/BLOCK=256/2-way j-split =
// 2048 blocks (8/CU, 32 waves/CU), row means forced to SGPR via
// readfirstlane so the kernel fits 64 VGPR without spilling.

constexpr float LOG2E = 1.4426950408889634f;
constexpr float LN2   = 0.6931471805599453f;

// ---------------- precompute: j-table [P][8] AoS + means SoA [4][P] --------
__global__ __launch_bounds__(256) void precompute_k(
    const float* __restrict__ particles,
    const float* __restrict__ samples,
    const float* __restrict__ weights,
    const float* __restrict__ log_weights,
    const float* __restrict__ A,
    const float* __restrict__ B,
    const float* __restrict__ log_sigma,
    float* __restrict__ jdata,   // [P][8]: {LOG2E*s0..s3, K*||s||^2, e^lw, e^w, 0}
    float* __restrict__ msoa,    // [4][P] scaled means
    int P)
{
    int i = blockIdx.x * blockDim.x + threadIdx.x;
    if (i >= P) return;

    const float K = -0.5f * LOG2E;

    float inv_s[4];
#pragma unroll
    for (int k = 0; k < 4; ++k)
        inv_s[k] = __builtin_amdgcn_exp2f(-log_sigma[k] * LOG2E);

    float4 sv = reinterpret_cast<const float4*>(samples)[i];
    float s0 = sv.x * inv_s[0], s1 = sv.y * inv_s[1];
    float s2 = sv.z * inv_s[2], s3 = sv.w * inv_s[3];
    float sn = s0*s0 + s1*s1 + s2*s2 + s3*s3;

    float4* jd = reinterpret_cast<float4*>(jdata + (size_t)i * 8);
    jd[0] = make_float4(LOG2E*s0, LOG2E*s1, LOG2E*s2, LOG2E*s3);
    jd[1] = make_float4(K * sn,
                        __builtin_amdgcn_exp2f(log_weights[i] * LOG2E),
                        __builtin_amdgcn_exp2f(weights[i] * LOG2E),
                        0.f);

    const float2* p2 = reinterpret_cast<const float2*>(particles) + (size_t)i * 3;
    float2 x01 = p2[0], x23 = p2[1], u01 = p2[2];
    float x[4] = {x01.x, x01.y, x23.x, x23.y};
    float u[2] = {u01.x, u01.y};
#pragma unroll
    for (int k = 0; k < 4; ++k) {
        float mean =       A[k*4+0] * x[0];
        mean = fmaf(A[k*4+1], x[1], mean);
        mean = fmaf(A[k*4+2], x[2], mean);
        mean = fmaf(A[k*4+3], x[3], mean);
        mean = fmaf(B[k*2+0], u[0], mean);
        mean = fmaf(B[k*2+1], u[1], mean);
        msoa[(size_t)k * P + i] = mean * inv_s[k];
    }
}

// ---------------- pair kernel: TR rows/block, NSPLIT-way j-split -----------
// grid = (NSPLIT, P/TR) = (2, 1024) = 2048 blocks of 256 -> 8 blocks/CU,
// 32 waves/CU (requires <=64 VGPR: means in SGPR via readfirstlane).
template <int TR, int BLOCK, int NSPLIT>
__global__ __launch_bounds__(BLOCK, 8) void pair_half(
    const float* __restrict__ jdata,   // [P][8]
    const float* __restrict__ msoa,    // [4][P]
    float* __restrict__ part1,         // [NSPLIT][P]
    float* __restrict__ part2,         // [NSPLIT][P]
    int P)
{
    constexpr int NW = BLOCK / 64;

    const int tid  = threadIdx.x;
    const int lane = tid & 63;
    const int wv   = tid >> 6;
    const int jc   = blockIdx.x;
    const int rowBase = blockIdx.y * TR;

    // block-uniform row means, forced to SGPR (frees ~32 VGPRs)
    float m0[TR], m1[TR], m2[TR], m3[TR], a1[TR], a2[TR];
#pragma unroll
    for (int r = 0; r < TR; ++r) {
        m0[r] = __builtin_amdgcn_readfirstlane(msoa[0 * (size_t)P + rowBase + r]);
        m1[r] = __builtin_amdgcn_readfirstlane(msoa[1 * (size_t)P + rowBase + r]);
        m2[r] = __builtin_amdgcn_readfirstlane(msoa[2 * (size_t)P + rowBase + r]);
        m3[r] = __builtin_amdgcn_readfirstlane(msoa[3 * (size_t)P + rowBase + r]);
        a1[r] = 0.f;
        a2[r] = 0.f;
    }

    // per-lane coalesced j-walk over this block's half of the table
    const int jspan = P / NSPLIT;               // 4096
    const float4* jf = reinterpret_cast<const float4*>(jdata) +
                       (size_t)jc * jspan * 2;
    const int iters = jspan / BLOCK;            // 16
#pragma unroll 4
    for (int it = 0; it < iters; ++it) {
        const int j = it * BLOCK + tid;
        float4 av = jf[2 * j];
        float4 bv = jf[2 * j + 1];
#pragma unroll
        for (int r = 0; r < TR; ++r) {
            float t = fmaf(m0[r], av.x, bv.x);
            t = fmaf(m1[r], av.y, t);
            t = fmaf(m2[r], av.z, t);
            t = fmaf(m3[r], av.w, t);
            float e = __builtin_amdgcn_exp2f(t);
            a1[r] = fmaf(e, bv.y, a1[r]);
            a2[r] = fmaf(e, bv.z, a2[r]);
        }
    }

    // ---- 64-lane butterfly per row (fixed order -> deterministic) ----
#pragma unroll
    for (int r = 0; r < TR; ++r) {
#pragma unroll
        for (int mask = 32; mask >= 1; mask >>= 1) {
            a1[r] += __shfl_xor(a1[r], mask, 64);
            a2[r] += __shfl_xor(a2[r], mask, 64);
        }
    }

    // ---- cross-wave combine via small LDS, fixed order ----
    __shared__ float red[NW][2 * TR];
    if (lane == 0) {
#pragma unroll
        for (int r = 0; r < TR; ++r) {
            red[wv][r]      = a1[r];
            red[wv][TR + r] = a2[r];
        }
    }
    __syncthreads();
    if (tid < TR) {
        float s1 = 0.f, s2 = 0.f;
#pragma unroll
        for (int w = 0; w < NW; ++w) {
            s1 += red[w][tid];
            s2 += red[w][TR + tid];
        }
        part1[(size_t)jc * P + rowBase + tid] = s1;
        part2[(size_t)jc * P + rowBase + tid] = s2;
    }
}

// ---------------- combine: depth-NSPLIT fixed-order sum + log-ratio --------
template <int NSPLIT>
__global__ __launch_bounds__(256) void combine_k(
    const float* __restrict__ part1,
    const float* __restrict__ part2,
    float* __restrict__ out, int P)
{
    int i = blockIdx.x * blockDim.x + threadIdx.x;
    if (i >= P) return;
    float s1 = 0.f, s2 = 0.f;
#pragma unroll
    for (int c = 0; c < NSPLIT; ++c) {
        s1 += part1[(size_t)c * P + i];
        s2 += part2[(size_t)c * P + i];
    }
    out[i] = (__builtin_amdgcn_logf(s2) - __builtin_amdgcn_logf(s1)) * LN2;
}

extern "C" void kernel_launch(void* const* d_in, const int* in_sizes, int n_in,
                              void* d_out, int out_size, void* d_ws, size_t ws_size,
                              hipStream_t stream)
{
    const float* particles   = (const float*)d_in[0];
    const float* samples     = (const float*)d_in[1];
    const float* weights     = (const float*)d_in[2];
    const float* log_weights = (const float*)d_in[3];
    const float* A           = (const float*)d_in[4];
    const float* B           = (const float*)d_in[5];
    const float* log_sigma   = (const float*)d_in[6];

    const int P = in_sizes[2];  // weights is (P,)

    constexpr int BLOCK = 256, TR = 8, NSPLIT = 2;

    // ws layout: jdata P*8 | msoa 4*P | part1 NSPLIT*P | part2 NSPLIT*P
    float* jdata = (float*)d_ws;
    float* msoa  = jdata + (size_t)P * 8;
    float* part1 = msoa + (size_t)P * 4;
    float* part2 = part1 + (size_t)NSPLIT * P;

    precompute_k<<<(P + 255) / 256, 256, 0, stream>>>(
        particles, samples, weights, log_weights, A, B, log_sigma,
        jdata, msoa, P);

    dim3 grid(NSPLIT, P / TR);                  // (2, 1024) = 2048 blocks
    pair_half<TR, BLOCK, NSPLIT><<<grid, BLOCK, 0, stream>>>(
        jdata, msoa, part1, part2, P);

    combine_k<NSPLIT><<<(P + 255) / 256, 256, 0, stream>>>(
        part1, part2, (float*)d_out, P);
}

// Round 13
// 27.052 us; speedup vs baseline: 1.1949x; 1.1883x over previous
//
#include <hip/hip_runtime.h>

// ParticleI2cCell: pairwise Gaussian loglik (P x P, D=4) + two row-LSEs.
// smoothed[i] = log(sum_j e_ij*exp(w_j)) - log(sum_j e_ij*exp(lw_j))
// e_ij = exp(m_i . s_j - ||s_j||^2/2)   [exp(-||m_i||^2/2) cancels in the
// log-ratio and is dropped].
//
// R12 lesson: per-pipe theories (trans, VALU-issue, occupancy, VMEM traffic,
// LDS-vs-VMEM feed) all falsified; totals decompose cleanly as
// pair(~17-19us) + ~3-5us per extra kernel dispatch in the replayed graph.
// R13: ONE kernel, zero workspace. Each block recomputes its 8 row-means
// from raw inputs (uniform scalar loads, once); the j-side is folded into
// the raw samples via M_k = L2E*m_k*inv_k^2 and cn = sum(-0.5*L2E*inv_k^2
// * sv_k^2), so the hot loop reads samples/weights/log_weights directly
// (24 B/j) and needs no precomputed table.

constexpr float LOG2E = 1.4426950408889634f;
constexpr float LN2   = 0.6931471805599453f;

// ---------------- single fused kernel --------------------------------------
// grid = P/TR = 1024 blocks of 256 -> 4 blocks/CU, 16 waves/CU.
// Thread t sweeps j = t + BLOCK*it (32 iters at P=8192).
template <int TR, int BLOCK>
__global__ __launch_bounds__(BLOCK, 4) void fused_all(
    const float* __restrict__ particles,   // [P][6]
    const float* __restrict__ samples,     // [P][4]
    const float* __restrict__ weights,     // [P]
    const float* __restrict__ log_weights, // [P]
    const float* __restrict__ A,           // [4][4]
    const float* __restrict__ B,           // [4][2]
    const float* __restrict__ log_sigma,   // [4]
    float* __restrict__ out, int P)
{
    constexpr int NW = BLOCK / 64;

    const int tid  = threadIdx.x;
    const int lane = tid & 63;
    const int wv   = tid >> 6;
    const int rowBase = blockIdx.x * TR;

    // ---- per-block uniform setup (scalar loads, ~100 cyc once) ----
    float inv2[4], Kinv[4];
#pragma unroll
    for (int k = 0; k < 4; ++k) {
        float iv = __builtin_amdgcn_exp2f(-log_sigma[k] * LOG2E);
        inv2[k] = iv * iv;
        Kinv[k] = -0.5f * LOG2E * inv2[k];
    }

    // row means for this block's TR rows: M_k[r] = L2E * mean_k * inv_k^2
    float M0[TR], M1[TR], M2[TR], M3[TR], a1[TR], a2[TR];
#pragma unroll
    for (int r = 0; r < TR; ++r) {
        const float* pr = particles + (size_t)(rowBase + r) * 6;
        float x0 = pr[0], x1 = pr[1], x2 = pr[2], x3 = pr[3];
        float u0 = pr[4], u1 = pr[5];
        float mk[4];
#pragma unroll
        for (int k = 0; k < 4; ++k) {
            float mean =       A[k*4+0] * x0;
            mean = fmaf(A[k*4+1], x1, mean);
            mean = fmaf(A[k*4+2], x2, mean);
            mean = fmaf(A[k*4+3], x3, mean);
            mean = fmaf(B[k*2+0], u0, mean);
            mean = fmaf(B[k*2+1], u1, mean);
            mk[k] = LOG2E * mean * inv2[k];
        }
        M0[r] = mk[0]; M1[r] = mk[1]; M2[r] = mk[2]; M3[r] = mk[3];
        a1[r] = 0.f;
        a2[r] = 0.f;
    }

    // ---- hot loop: per-lane coalesced reads of raw inputs ----
    const float4* sf = reinterpret_cast<const float4*>(samples);
    const int iters = P / BLOCK;     // 32 at P=8192
#pragma unroll 4
    for (int it = 0; it < iters; ++it) {
        const int j = it * BLOCK + tid;
        float4 sv = sf[j];
        float w  = weights[j];
        float lw = log_weights[j];
        // cn = sum_k Kinv_k * sv_k^2   (= -0.5*L2E*||s||^2)
        float cn = Kinv[0] * sv.x * sv.x;
        cn = fmaf(Kinv[1] * sv.y, sv.y, cn);
        cn = fmaf(Kinv[2] * sv.z, sv.z, cn);
        cn = fmaf(Kinv[3] * sv.w, sv.w, cn);
        float elw = __builtin_amdgcn_exp2f(lw * LOG2E);
        float ew  = __builtin_amdgcn_exp2f(w * LOG2E);
#pragma unroll
        for (int r = 0; r < TR; ++r) {
            float t = fmaf(M0[r], sv.x, cn);
            t = fmaf(M1[r], sv.y, t);
            t = fmaf(M2[r], sv.z, t);
            t = fmaf(M3[r], sv.w, t);
            float e = __builtin_amdgcn_exp2f(t);
            a1[r] = fmaf(e, elw, a1[r]);
            a2[r] = fmaf(e, ew,  a2[r]);
        }
    }

    // ---- 64-lane butterfly per row (fixed order -> deterministic) ----
#pragma unroll
    for (int r = 0; r < TR; ++r) {
#pragma unroll
        for (int mask = 32; mask >= 1; mask >>= 1) {
            a1[r] += __shfl_xor(a1[r], mask, 64);
            a2[r] += __shfl_xor(a2[r], mask, 64);
        }
    }

    // ---- cross-wave combine via small LDS, fixed order ----
    __shared__ float red[NW][2 * TR];
    if (lane == 0) {
#pragma unroll
        for (int r = 0; r < TR; ++r) {
            red[wv][r]      = a1[r];
            red[wv][TR + r] = a2[r];
        }
    }
    __syncthreads();
    if (tid < TR) {
        float s1 = 0.f, s2 = 0.f;
#pragma unroll
        for (int w = 0; w < NW; ++w) {
            s1 += red[w][tid];
            s2 += red[w][TR + tid];
        }
        out[rowBase + tid] =
            (__builtin_amdgcn_logf(s2) - __builtin_amdgcn_logf(s1)) * LN2;
    }
}

extern "C" void kernel_launch(void* const* d_in, const int* in_sizes, int n_in,
                              void* d_out, int out_size, void* d_ws, size_t ws_size,
                              hipStream_t stream)
{
    const float* particles   = (const float*)d_in[0];
    const float* samples     = (const float*)d_in[1];
    const float* weights     = (const float*)d_in[2];
    const float* log_weights = (const float*)d_in[3];
    const float* A           = (const float*)d_in[4];
    const float* B           = (const float*)d_in[5];
    const float* log_sigma   = (const float*)d_in[6];

    const int P = in_sizes[2];  // weights is (P,)

    constexpr int BLOCK = 256, TR = 8;

    fused_all<TR, BLOCK><<<P / TR, BLOCK, 0, stream>>>(
        particles, samples, weights, log_weights, A, B, log_sigma,
        (float*)d_out, P);
}